// Round 3
// baseline (246.274 us; speedup 1.0000x reference)
//
#include <hip/hip_runtime.h>
#include <cstdint>
#include <cstddef>

typedef unsigned long long u64;

#define B_SZ 4096
#define C_SZ 1000
#define V_SZ 8000
#define RW 128              // padded row stride in u64 (125 used)
#define THRESHF 0.8f
#define SCALEF 0.1f

#define OFF_CI 0
#define OFF_CS (B_SZ * 5)
#define OFF_HI (2 * B_SZ * 5)
#define OFF_HS (3 * B_SZ * 5)
#define OFF_C1 (3 * B_SZ * 5 + B_SZ)
#define OFF_C2 (3 * B_SZ * 5 + 2 * B_SZ)

// ---------------- pack matrix rows into bitmasks ----------------
__global__ __launch_bounds__(256) void pack_kernel(const int* __restrict__ mat,
                                                   u64* __restrict__ packed) {
  const int c = blockIdx.x;
  const int tid = threadIdx.x;
  const int lane = tid & 63;
  const int wv = tid >> 6;
  const int* row = mat + (size_t)c * V_SZ;
  for (int base = 0; base < 8192; base += 256) {
    const int k = base + tid;
    int v = 0;
    if (k < V_SZ) v = row[k];
    u64 msk = __ballot(v != 0);
    if (lane == 0) packed[(size_t)c * RW + ((base >> 6) + wv)] = msk;
  }
}

// ---------------- class softmax + top5 (UNCHANGED - bit-exact) ----------------
__global__ __launch_bounds__(256) void class_topk_kernel(const float* __restrict__ logits,
                                                         float* __restrict__ out) {
  const int b = blockIdx.x;
  const int tid = threadIdx.x;
  const int lane = tid & 63;
  const int wv = tid >> 6;
  const float* row = logits + (size_t)b * V_SZ;
  float v[32];
#pragma unroll
  for (int q = 0; q < 32; ++q) {
    int k = tid + (q << 8);
    v[q] = (k < V_SZ) ? row[k] : -INFINITY;
  }
  __shared__ float sred[4];
  __shared__ int sredi[4];
  float lm = -INFINITY;
#pragma unroll
  for (int q = 0; q < 32; ++q) lm = fmaxf(lm, v[q]);
#pragma unroll
  for (int o = 32; o >= 1; o >>= 1) lm = fmaxf(lm, __shfl_xor(lm, o));
  if (lane == 0) sred[wv] = lm;
  __syncthreads();
  const float m = fmaxf(fmaxf(sred[0], sred[1]), fmaxf(sred[2], sred[3]));
  float ls = 0.f;
#pragma unroll
  for (int q = 0; q < 32; ++q) ls += expf(v[q] - m);
#pragma unroll
  for (int o = 32; o >= 1; o >>= 1) ls += __shfl_xor(ls, o);
  __syncthreads();
  if (lane == 0) sred[wv] = ls;
  __syncthreads();
  const float ssum = sred[0] + sred[1] + sred[2] + sred[3];
  for (int r = 0; r < 5; ++r) {
    float bv = -INFINITY;
    int bi = 0;
#pragma unroll
    for (int q = 0; q < 32; ++q) {
      if (v[q] > bv) { bv = v[q]; bi = tid + (q << 8); }
    }
#pragma unroll
    for (int o = 32; o >= 1; o >>= 1) {
      float ov = __shfl_xor(bv, o);
      int oi = __shfl_xor(bi, o);
      if (ov > bv || (ov == bv && oi < bi)) { bv = ov; bi = oi; }
    }
    __syncthreads();
    if (lane == 0) { sred[wv] = bv; sredi[wv] = bi; }
    __syncthreads();
    bv = sred[0]; bi = sredi[0];
#pragma unroll
    for (int w = 1; w < 4; ++w) {
      if (sred[w] > bv || (sred[w] == bv && sredi[w] < bi)) { bv = sred[w]; bi = sredi[w]; }
    }
    if ((bi & 255) == tid) {
      const int sl = bi >> 8;
#pragma unroll
      for (int q = 0; q < 32; ++q)
        if (q == sl) v[q] = -INFINITY;
    }
    if (tid == 0) {
      out[OFF_CI + b * 5 + r] = (float)bi;
      out[OFF_CS + b * 5 + r] = expf(bv - m) / ssum;
    }
  }
}

// ---------------- per-sample component decode ----------------
__global__ __launch_bounds__(256) void decode_kernel(const float* __restrict__ compo_logits,
                                                     const float* __restrict__ co_occ,
                                                     const u64* __restrict__ packed,
                                                     float* __restrict__ out) {
  const int b = blockIdx.x;
  const int tid = threadIdx.x;
  const int lane = tid & 63;
  const int wv = tid >> 6;

  __shared__ float s_sc[1024];
  __shared__ int s_list[C_SZ];
  __shared__ u64 s_rows[16][128];
  __shared__ float s_wv_v[4][16];
  __shared__ int s_wv_i[4][16];
  __shared__ float s_gv[16];
  __shared__ int s_gi[16];
  __shared__ float red_v[4];
  __shared__ int red_i[4];
  __shared__ int red_n[4];
  __shared__ int s_nsel2;
  __shared__ int s_mxi;
  __shared__ float s_mxv;
  __shared__ int s_nadj;
  __shared__ int s_ctl;

  // ---- A1: sigmoid (vectorized) ----
  const float* lg = compo_logits + (size_t)b * C_SZ;
  if (tid < 250) {
    float4 x = ((const float4*)lg)[tid];
    s_sc[4 * tid + 0] = 1.0f / (1.0f + expf(-x.x));
    s_sc[4 * tid + 1] = 1.0f / (1.0f + expf(-x.y));
    s_sc[4 * tid + 2] = 1.0f / (1.0f + expf(-x.z));
    s_sc[4 * tid + 3] = 1.0f / (1.0f + expf(-x.w));
  } else {
    s_sc[4 * tid + 0] = -INFINITY;
    s_sc[4 * tid + 1] = -INFINITY;
    s_sc[4 * tid + 2] = -INFINITY;
    s_sc[4 * tid + 3] = -INFINITY;
  }
  __syncthreads();

  // ---- A2: compact selected (pre-adjust), ascending ----
  if (wv == 0) {
    int off = 0;
    for (int base = 0; base < C_SZ; base += 64) {
      const int k = base + lane;
      float mv = (k < C_SZ) ? s_sc[k] : -INFINITY;
      bool sel = (k < C_SZ) && (mv > THRESHF);
      u64 msk = __ballot(sel);
      int rank = __popcll(msk & ((1ull << lane) - 1ull));
      if (sel) s_list[off + rank] = k;
      off += __popcll(msk);
    }
    if (lane == 0) s_nadj = off;
  }
  __syncthreads();
  const int nadj = s_nadj;

  // ---- A3: adj matvec, float4 loads, unroll 4 (ascending-e order per column) ----
  float a0 = 0.f, a1 = 0.f, a2 = 0.f, a3 = 0.f;
  if (tid < 250) {
    const float4* cov = (const float4*)co_occ;
    int e = 0;
    for (; e + 4 <= nadj; e += 4) {
      int i0 = s_list[e], i1 = s_list[e + 1], i2 = s_list[e + 2], i3 = s_list[e + 3];
      float m0 = s_sc[i0], m1 = s_sc[i1], m2 = s_sc[i2], m3 = s_sc[i3];
      float4 v0 = cov[i0 * 250 + tid];
      float4 v1 = cov[i1 * 250 + tid];
      float4 v2 = cov[i2 * 250 + tid];
      float4 v3 = cov[i3 * 250 + tid];
      a0 += m0 * v0.x; a0 += m1 * v1.x; a0 += m2 * v2.x; a0 += m3 * v3.x;
      a1 += m0 * v0.y; a1 += m1 * v1.y; a1 += m2 * v2.y; a1 += m3 * v3.y;
      a2 += m0 * v0.z; a2 += m1 * v1.z; a2 += m2 * v2.z; a2 += m3 * v3.z;
      a3 += m0 * v0.w; a3 += m1 * v1.w; a3 += m2 * v2.w; a3 += m3 * v3.w;
    }
    for (; e < nadj; ++e) {
      int i = s_list[e];
      float m = s_sc[i];
      float4 v = cov[i * 250 + tid];
      a0 += m * v.x; a1 += m * v.y; a2 += m * v.z; a3 += m * v.w;
    }
  }
  __syncthreads();  // all reads of pre-adjust s_sc complete before overwrite

  // ---- A4: final scores, block argmax (tie->lowest idx), count(>THRESH) ----
  float bv = -INFINITY;
  int bi = 0;
  int cnt = 0;
  if (tid < 250) {
    float sc;
    sc = s_sc[4 * tid + 0] + SCALEF * a0; s_sc[4 * tid + 0] = sc;
    if (sc > THRESHF) cnt++;
    if (sc > bv) { bv = sc; bi = 4 * tid + 0; }
    sc = s_sc[4 * tid + 1] + SCALEF * a1; s_sc[4 * tid + 1] = sc;
    if (sc > THRESHF) cnt++;
    if (sc > bv) { bv = sc; bi = 4 * tid + 1; }
    sc = s_sc[4 * tid + 2] + SCALEF * a2; s_sc[4 * tid + 2] = sc;
    if (sc > THRESHF) cnt++;
    if (sc > bv) { bv = sc; bi = 4 * tid + 2; }
    sc = s_sc[4 * tid + 3] + SCALEF * a3; s_sc[4 * tid + 3] = sc;
    if (sc > THRESHF) cnt++;
    if (sc > bv) { bv = sc; bi = 4 * tid + 3; }
  }
#pragma unroll
  for (int o = 32; o >= 1; o >>= 1) {
    float ov = __shfl_xor(bv, o);
    int oi = __shfl_xor(bi, o);
    cnt += __shfl_xor(cnt, o);
    if (ov > bv || (ov == bv && oi < bi)) { bv = ov; bi = oi; }
  }
  if (lane == 0) { red_v[wv] = bv; red_i[wv] = bi; red_n[wv] = cnt; }
  __syncthreads();
  if (tid == 0) {
    float mv = red_v[0];
    int mi = red_i[0];
    for (int w = 1; w < 4; ++w)
      if (red_v[w] > mv || (red_v[w] == mv && red_i[w] < mi)) { mv = red_v[w]; mi = red_i[w]; }
    s_mxv = mv; s_mxi = mi;
    s_nsel2 = red_n[0] + red_n[1] + red_n[2] + red_n[3];
  }
  __syncthreads();
  const float mxv = s_mxv;
  const int mxi = s_mxi;
  const int nsel = s_nsel2;

  // extraction registers: wave wv owns cols [256wv, 256wv+256)
  const int ebase = wv << 8;
  float r0 = s_sc[ebase + lane];
  float r1 = s_sc[ebase + lane + 64];
  float r2 = s_sc[ebase + lane + 128];
  float r3 = s_sc[ebase + lane + 192];

  // wave0 chain state
  u64 acc0 = ~0ull, acc1 = ~0ull;
  float prev_last = mxv;
  float hitscore = mxv;

  for (int batch = 0; batch < 64; ++batch) {
    // (a) per-wave top-16 extraction (sorted desc, tie->lowest col)
    {
      int rd = 0;
      for (; rd < 16; ++rd) {
        float ev = r0;
        int ei = ebase + lane;
        if (r1 > ev) { ev = r1; ei = ebase + lane + 64; }
        if (r2 > ev) { ev = r2; ei = ebase + lane + 128; }
        if (r3 > ev) { ev = r3; ei = ebase + lane + 192; }
#pragma unroll
        for (int o = 32; o >= 1; o >>= 1) {
          float ov = __shfl_xor(ev, o);
          int oi = __shfl_xor(ei, o);
          if (ov > ev || (ov == ev && oi < ei)) { ev = ov; ei = oi; }
        }
        if (!(ev > THRESHF)) break;
        if (lane == 0) { s_wv_v[wv][rd] = ev; s_wv_i[wv][rd] = ei; }
        int d = ei - ebase;
        if ((d & 63) == lane) {
          if (d < 64) r0 = -INFINITY;
          else if (d < 128) r1 = -INFINITY;
          else if (d < 192) r2 = -INFINITY;
          else r3 = -INFINITY;
        }
      }
      if (lane == 0)
        for (; rd < 16; ++rd) s_wv_v[wv][rd] = -INFINITY;
    }
    __syncthreads();
    // (b) merge in wave0 -> global next-16 sorted
    if (wv == 0) {
      float cv = s_wv_v[lane >> 4][lane & 15];
      int ci = s_wv_i[lane >> 4][lane & 15];
      int rd = 0;
      for (; rd < 16; ++rd) {
        float ev = cv;
        int ei = ci;
#pragma unroll
        for (int o = 32; o >= 1; o >>= 1) {
          float ov = __shfl_xor(ev, o);
          int oi = __shfl_xor(ei, o);
          if (ov > ev || (ov == ev && oi < ei)) { ev = ov; ei = oi; }
        }
        if (!(ev > THRESHF)) break;
        if (lane == 0) { s_gi[rd] = ei; s_gv[rd] = ev; }
        if (ci == ei) cv = -INFINITY;
      }
      if (lane == 0) {
        for (; rd < 16; ++rd) s_gi[rd] = -1;
        if (nsel == 0 && batch == 0) { s_gi[0] = mxi; s_gv[0] = mxv; }
      }
    }
    __syncthreads();
    // (c) RESTORE candidates this wave extracted but the merge did NOT consume
    //     (they were cleared from regs at extraction time; without this they'd be lost
    //      and batch>=1 would AND the wrong rows)
    for (int j = 0; j < 16; ++j) {
      float val = s_wv_v[wv][j];
      if (val == -INFINITY) break;          // candidates are desc-sorted; fillers are -inf
      int idx = s_wv_i[wv][j];
      bool consumed = false;
#pragma unroll
      for (int k = 0; k < 16; ++k) consumed |= (s_gi[k] == idx);
      if (!consumed) {
        int d = idx - ebase;
        if ((d & 63) == lane) {
          if (d < 64) r0 = val;
          else if (d < 128) r1 = val;
          else if (d < 192) r2 = val;
          else r3 = val;
        }
      }
    }
    // cooperative row load into LDS
    {
      int k = tid >> 4;
      int g = s_gi[k];
      if (g >= 0) {
        const u64* src = packed + (size_t)g * RW + ((tid & 15) << 3);
        u64* dst = &s_rows[k][(tid & 15) << 3];
#pragma unroll
        for (int w = 0; w < 8; ++w) dst[w] = src[w];
      }
    }
    __syncthreads();
    // (d) wave0: prefix-AND chain + stop decision
    if (wv == 0) {
      u64 bal = __ballot(lane < 16 && s_gi[lane] >= 0);
      int take = __popcll(bal);
      u64 na0 = acc0, na1 = acc1;
      u64 pk0 = 0, pk1 = 0, pk2 = 0, pk3 = 0;
      for (int k = 0; k < take; ++k) {
        na0 &= s_rows[k][lane];
        na1 &= s_rows[k][64 + lane];
        u64 pc = (u64)(__popcll(na0) + __popcll(na1));
        int sh = (k & 3) << 4;
        if (k < 4) pk0 |= pc << sh;
        else if (k < 8) pk1 |= pc << sh;
        else if (k < 12) pk2 |= pc << sh;
        else pk3 |= pc << sh;
      }
#pragma unroll
      for (int o = 32; o >= 1; o >>= 1) {
        pk0 += __shfl_xor(pk0, o);
        pk1 += __shfl_xor(pk1, o);
        pk2 += __shfl_xor(pk2, o);
        pk3 += __shfl_xor(pk3, o);
      }
      int kstar = -1;
      unsigned pcs = 0;
      for (int k = 0; k < take; ++k) {
        int sh = (k & 3) << 4;
        u64 w = (k < 4) ? pk0 : ((k < 8) ? pk1 : ((k < 12) ? pk2 : pk3));
        unsigned pcv = (unsigned)((w >> sh) & 0xffffull);
        if (pcv <= 1u) { kstar = k; pcs = pcv; break; }
      }
      int stop, kfin;
      if (take == 0) { stop = 1; kfin = 0; hitscore = prev_last; }
      else if (kstar >= 0) {
        if (pcs == 0) {
          stop = 1;
          if (kstar == 0) { kfin = 0; hitscore = prev_last; }
          else { kfin = kstar; hitscore = s_gv[kstar - 1]; }
        } else { stop = 1; kfin = kstar + 1; hitscore = s_gv[kstar]; }
      } else if (take < 16) { stop = 1; kfin = take; hitscore = s_gv[take - 1]; }
      else { stop = 0; kfin = 16; }
      for (int k = 0; k < kfin; ++k) {
        acc0 &= s_rows[k][lane];
        acc1 &= s_rows[k][64 + lane];
      }
      if (!stop) prev_last = s_gv[15];
      if (lane == 0) s_ctl = stop;
    }
    __syncthreads();
    if (s_ctl) break;
  }

  // ---- emission (wave0) ----
  if (wv == 0) {
    u64 h0 = acc0, h1 = acc1;
    const int c0 = __popcll(h0), c1 = __popcll(h1);
    int sc0 = c0;
#pragma unroll
    for (int o = 1; o < 64; o <<= 1) {
      int n = __shfl_up(sc0, o);
      if (lane >= o) sc0 += n;
    }
    const int tot0 = __shfl(sc0, 63);
    const int pre0 = sc0 - c0;
    int sc1 = c1;
#pragma unroll
    for (int o = 1; o < 64; o <<= 1) {
      int n = __shfl_up(sc1, o);
      if (lane >= o) sc1 += n;
    }
    const int tot = tot0 + __shfl(sc1, 63);
    const int pre1 = tot0 + sc1 - c1;
    {
      u64 x = h0;
      int r = pre0;
      while (x && r < 5) {
        int bp = __ffsll((unsigned long long)x) - 1;
        out[OFF_HI + b * 5 + r] = (float)((lane << 6) + bp);
        x &= x - 1;
        ++r;
      }
      x = h1;
      r = pre1;
      while (x && r < 5) {
        int bp = __ffsll((unsigned long long)x) - 1;
        out[OFF_HI + b * 5 + r] = (float)(((64 + lane) << 6) + bp);
        x &= x - 1;
        ++r;
      }
    }
    int fb = 0x7fffffff;
    if (c0) fb = (lane << 6) + __ffsll((unsigned long long)h0) - 1;
    else if (c1) fb = ((64 + lane) << 6) + __ffsll((unsigned long long)h1) - 1;
#pragma unroll
    for (int o = 32; o >= 1; o >>= 1) fb = min(fb, __shfl_xor(fb, o));
    if (lane == 0) {
      const int num_hit = tot < 5 ? tot : 5;
      for (int r = num_hit; r < 5; ++r) out[OFF_HI + b * 5 + r] = -1.0f;
      out[OFF_HS + b] = hitscore;
      const float ci0 = out[OFF_CI + b * 5];
      const float cs0 = out[OFF_CS + b * 5];
      out[OFF_C1 + b] = (num_hit == 1) ? (float)fb : ci0;
      out[OFF_C2 + b] = (cs0 < 0.85f && num_hit == 1) ? (float)fb : ci0;
    }
  }
}

extern "C" void kernel_launch(void* const* d_in, const int* in_sizes, int n_in,
                              void* d_out, int out_size, void* d_ws, size_t ws_size,
                              hipStream_t stream) {
  (void)in_sizes; (void)n_in; (void)out_size; (void)ws_size;
  const float* class_logits = (const float*)d_in[0];
  const float* compo_logits = (const float*)d_in[1];
  const float* co_occ = (const float*)d_in[2];
  const int* mat = (const int*)d_in[3];
  float* out = (float*)d_out;
  u64* packed = (u64*)d_ws;  // 1000 * 128 * 8 B = 1 MB

  pack_kernel<<<C_SZ, 256, 0, stream>>>(mat, packed);
  class_topk_kernel<<<B_SZ, 256, 0, stream>>>(class_logits, out);
  decode_kernel<<<B_SZ, 256, 0, stream>>>(compo_logits, co_occ, packed, out);
}

// Round 4
// 222.934 us; speedup vs baseline: 1.1047x; 1.1047x over previous
//
#include <hip/hip_runtime.h>
#include <cstdint>
#include <cstddef>

typedef unsigned long long u64;

#define B_SZ 4096
#define C_SZ 1000
#define V_SZ 8000
#define RW 128              // padded row stride in u64 (125 used, rest zero)
#define THRESHF 0.8f
#define SCALEF 0.1f
#define S_MV 8              // samples per matvec block

#define OFF_CI 0
#define OFF_CS (B_SZ * 5)
#define OFF_HI (2 * B_SZ * 5)
#define OFF_HS (3 * B_SZ * 5)
#define OFF_C1 (3 * B_SZ * 5 + B_SZ)
#define OFF_C2 (3 * B_SZ * 5 + 2 * B_SZ)

// ---------------- pack matrix rows into bitmasks ----------------
__global__ __launch_bounds__(256) void pack_kernel(const int* __restrict__ mat,
                                                   u64* __restrict__ packed) {
  const int c = blockIdx.x;
  const int tid = threadIdx.x;
  const int lane = tid & 63;
  const int wv = tid >> 6;
  const int* row = mat + (size_t)c * V_SZ;
  for (int base = 0; base < 8192; base += 256) {
    const int k = base + tid;
    int v = 0;
    if (k < V_SZ) v = row[k];
    u64 msk = __ballot(v != 0);
    if (lane == 0) packed[(size_t)c * RW + ((base >> 6) + wv)] = msk;
  }
}

// ---------------- class softmax + top5 (float4 loads) ----------------
__global__ __launch_bounds__(256) void class_topk_kernel(const float* __restrict__ logits,
                                                         float* __restrict__ out) {
  const int b = blockIdx.x;
  const int tid = threadIdx.x;
  const int lane = tid & 63;
  const int wv = tid >> 6;
  const float* row = logits + (size_t)b * V_SZ;
  float v[32];
#pragma unroll
  for (int f = 0; f < 8; ++f) {
    const int base = (f << 10) + (tid << 2);
    if (base < V_SZ) {
      float4 x = *(const float4*)(row + base);
      v[4 * f + 0] = x.x; v[4 * f + 1] = x.y; v[4 * f + 2] = x.z; v[4 * f + 3] = x.w;
    } else {
      v[4 * f + 0] = -INFINITY; v[4 * f + 1] = -INFINITY;
      v[4 * f + 2] = -INFINITY; v[4 * f + 3] = -INFINITY;
    }
  }
  __shared__ float sred[4];
  __shared__ int sredi[4];
  float lm = -INFINITY;
#pragma unroll
  for (int q = 0; q < 32; ++q) lm = fmaxf(lm, v[q]);
#pragma unroll
  for (int o = 32; o >= 1; o >>= 1) lm = fmaxf(lm, __shfl_xor(lm, o));
  if (lane == 0) sred[wv] = lm;
  __syncthreads();
  const float m = fmaxf(fmaxf(sred[0], sred[1]), fmaxf(sred[2], sred[3]));
  float ls = 0.f;
#pragma unroll
  for (int q = 0; q < 32; ++q) ls += expf(v[q] - m);
#pragma unroll
  for (int o = 32; o >= 1; o >>= 1) ls += __shfl_xor(ls, o);
  __syncthreads();
  if (lane == 0) sred[wv] = ls;
  __syncthreads();
  const float ssum = sred[0] + sred[1] + sred[2] + sred[3];
  for (int r = 0; r < 5; ++r) {
    float bv = -INFINITY;
    int bi = 0;
#pragma unroll
    for (int q = 0; q < 32; ++q) {
      const int idx = ((q >> 2) << 10) + (tid << 2) + (q & 3);
      if (v[q] > bv) { bv = v[q]; bi = idx; }
    }
#pragma unroll
    for (int o = 32; o >= 1; o >>= 1) {
      float ov = __shfl_xor(bv, o);
      int oi = __shfl_xor(bi, o);
      if (ov > bv || (ov == bv && oi < bi)) { bv = ov; bi = oi; }
    }
    __syncthreads();
    if (lane == 0) { sred[wv] = bv; sredi[wv] = bi; }
    __syncthreads();
    bv = sred[0]; bi = sredi[0];
#pragma unroll
    for (int w = 1; w < 4; ++w) {
      if (sred[w] > bv || (sred[w] == bv && sredi[w] < bi)) { bv = sred[w]; bi = sredi[w]; }
    }
    if (((bi & 1023) >> 2) == tid) {
      const int sl = ((bi >> 10) << 2) | (bi & 3);
#pragma unroll
      for (int q = 0; q < 32; ++q)
        if (q == sl) v[q] = -INFINITY;
    }
    if (tid == 0) {
      out[OFF_CI + b * 5 + r] = (float)bi;
      out[OFF_CS + b * 5 + r] = expf(bv - m) / ssum;
    }
  }
}

// ---------------- adj matvec: 8 samples/block, row-skip by bitmask ----------------
__global__ __launch_bounds__(256) void matvec_kernel(const float* __restrict__ compo_logits,
                                                     const float* __restrict__ co_occ,
                                                     float* __restrict__ sc_arr) {
  const int b0 = blockIdx.x * S_MV;
  const int tid = threadIdx.x;
  const int lane = tid & 63;
  const int w = tid >> 6;
  __shared__ float s_sc[S_MV][C_SZ];   // sigmoid scores
  __shared__ unsigned s_bm[C_SZ];      // per-row selection bitmask over 8 samples

  // phase A: sigmoid
  for (int idx = tid; idx < S_MV * 250; idx += 256) {
    const int sp = idx / 250;
    const int f = idx - sp * 250;
    float4 x = ((const float4*)(compo_logits + (size_t)(b0 + sp) * C_SZ))[f];
    s_sc[sp][4 * f + 0] = 1.0f / (1.0f + expf(-x.x));
    s_sc[sp][4 * f + 1] = 1.0f / (1.0f + expf(-x.y));
    s_sc[sp][4 * f + 2] = 1.0f / (1.0f + expf(-x.z));
    s_sc[sp][4 * f + 3] = 1.0f / (1.0f + expf(-x.w));
  }
  __syncthreads();
  // phase B: build row bitmasks
  for (int i = tid; i < C_SZ; i += 256) {
    unsigned mk = 0;
#pragma unroll
    for (int sp = 0; sp < S_MV; ++sp) mk |= (s_sc[sp][i] > THRESHF ? 1u : 0u) << sp;
    s_bm[i] = mk;
  }
  __syncthreads();
  // phase C: accumulate adj (wave w owns samples w and w+4; lane owns cols 16l..16l+15)
  float acc[2][16];
#pragma unroll
  for (int s = 0; s < 2; ++s)
#pragma unroll
    for (int j = 0; j < 16; ++j) acc[s][j] = 0.0f;
  const int cb = lane << 4;
  const unsigned wsel = 0x11u << w;
  for (int i = 0; i < C_SZ; ++i) {
    const unsigned bmv = s_bm[i];
    if (!(bmv & wsel)) continue;
    float cv[16];
#pragma unroll
    for (int f = 0; f < 4; ++f) {
      const int base = cb + 4 * f;
      if (base < C_SZ) {
        float4 x = *(const float4*)(co_occ + (size_t)i * C_SZ + base);
        cv[4 * f + 0] = x.x; cv[4 * f + 1] = x.y; cv[4 * f + 2] = x.z; cv[4 * f + 3] = x.w;
      } else {
        cv[4 * f + 0] = 0.f; cv[4 * f + 1] = 0.f; cv[4 * f + 2] = 0.f; cv[4 * f + 3] = 0.f;
      }
    }
#pragma unroll
    for (int spl = 0; spl < 2; ++spl) {
      const int sp = w + 4 * spl;
      if (bmv & (1u << sp)) {
        const float ms = s_sc[sp][i];
#pragma unroll
        for (int j = 0; j < 16; ++j) acc[spl][j] += ms * cv[j];
      }
    }
  }
  // phase D: final scores to ws
#pragma unroll
  for (int spl = 0; spl < 2; ++spl) {
    const int sp = w + 4 * spl;
    float* dst = sc_arr + (size_t)(b0 + sp) * C_SZ;
#pragma unroll
    for (int f = 0; f < 4; ++f) {
      const int base = cb + 4 * f;
      if (base < C_SZ) {
        float4 o;
        o.x = s_sc[sp][base + 0] + SCALEF * acc[spl][4 * f + 0];
        o.y = s_sc[sp][base + 1] + SCALEF * acc[spl][4 * f + 1];
        o.z = s_sc[sp][base + 2] + SCALEF * acc[spl][4 * f + 2];
        o.w = s_sc[sp][base + 3] + SCALEF * acc[spl][4 * f + 3];
        *(float4*)(dst + base) = o;
      }
    }
  }
}

// ---------------- tail: one wave per sample ----------------
__global__ __launch_bounds__(256) void tail_kernel(const float* __restrict__ sc_arr,
                                                   const u64* __restrict__ packed,
                                                   float* __restrict__ out) {
  const int b = blockIdx.x * 4 + (threadIdx.x >> 6);
  const int lane = threadIdx.x & 63;
  const float* sc = sc_arr + (size_t)b * C_SZ;
  u64 key[16];
  unsigned avail = 0;
  int cnt = 0;
  u64 kb = 0;
#pragma unroll
  for (int q = 0; q < 16; ++q) {
    const int col = lane + (q << 6);
    if (col < C_SZ) {
      const float s = sc[col];
      const u64 k = ((u64)__float_as_uint(s) << 32) | (u64)(0xFFFFFFFFu - (unsigned)col);
      key[q] = k;
      if (k > kb) kb = k;
      if (s > THRESHF) { avail |= 1u << q; cnt++; }
    } else key[q] = 0;
  }
  // global argmax (ties -> lowest col via inverted low word)
  u64 mk = kb;
#pragma unroll
  for (int o = 32; o >= 1; o >>= 1) { u64 t = __shfl_xor(mk, o); if (t > mk) mk = t; }
  const float mxv = __uint_as_float((unsigned)(mk >> 32));
  const int mxi = (int)(0xFFFFFFFFu - (unsigned)(mk & 0xFFFFFFFFull));
#pragma unroll
  for (int o = 32; o >= 1; o >>= 1) cnt += __shfl_xor(cnt, o);
  const int nsel = cnt;
  if ((mxi & 63) == lane) avail &= ~(1u << (mxi >> 6));
  // initial hit = row[mxi]
  const u64* pr = packed + (size_t)mxi * RW;
  u64 h0 = pr[lane], h1 = pr[64 + lane];
  int pc = __popcll(h0) + __popcll(h1);
#pragma unroll
  for (int o = 32; o >= 1; o >>= 1) pc += __shfl_xor(pc, o);
  int i = 1;
  float last_val = mxv;
  if (nsel >= 2 && pc > 1) {
    for (;;) {
      int kt = (nsel - i < 8) ? (nsel - i) : 8;
      float cval[8];
      int cidx[8];
      u64 rl[8], rh[8];
      float lastc = last_val;
      int kv = 0;
#pragma unroll
      for (int k = 0; k < 8; ++k) {
        cval[k] = 0.0f; cidx[k] = -1;
        if (k < kt) {
          u64 lm = 0;
#pragma unroll
          for (int q = 0; q < 16; ++q)
            if (avail & (1u << q)) { if (key[q] > lm) lm = key[q]; }
          u64 ck = lm;
#pragma unroll
          for (int o = 32; o >= 1; o >>= 1) { u64 t = __shfl_xor(ck, o); if (t > ck) ck = t; }
          if (ck != 0) {
            cval[k] = __uint_as_float((unsigned)(ck >> 32));
            cidx[k] = (int)(0xFFFFFFFFu - (unsigned)(ck & 0xFFFFFFFFull));
            if ((cidx[k] & 63) == lane) avail &= ~(1u << (cidx[k] >> 6));
            lastc = cval[k];
            kv = k + 1;
          }
        }
      }
      kt = kv;
      if (kt == 0) break;
      // prefetch all batch rows
#pragma unroll
      for (int k = 0; k < 8; ++k) {
        if (k < kt) {
          const u64* rp = packed + (size_t)cidx[k] * RW;
          rl[k] = rp[lane]; rh[k] = rp[64 + lane];
        } else { rl[k] = ~0ull; rh[k] = ~0ull; }
      }
      // AND chain with packed per-step popcounts
      u64 c0 = h0, c1 = h1, pk0 = 0, pk1 = 0;
#pragma unroll
      for (int k = 0; k < 8; ++k) {
        c0 &= rl[k]; c1 &= rh[k];
        const u64 p = (u64)(__popcll(c0) + __popcll(c1));
        if (k < 4) pk0 |= p << (k * 16); else pk1 |= p << ((k - 4) * 16);
      }
#pragma unroll
      for (int o = 32; o >= 1; o >>= 1) { pk0 += __shfl_xor(pk0, o); pk1 += __shfl_xor(pk1, o); }
      int kstar = -1;
      unsigned pcv = 0;
#pragma unroll
      for (int k = 0; k < 8; ++k) {
        if (k < kt && kstar < 0) {
          const unsigned f = (unsigned)(((k < 4 ? pk0 : pk1) >> ((k & 3) * 16)) & 0xFFFFull);
          if (f <= 1u) { kstar = k; pcv = f; }
        }
      }
      if (kstar >= 0) {
        float vk = 0.f, vkm1 = last_val;
#pragma unroll
        for (int k = 0; k < 8; ++k)
          if (k == kstar) { vk = cval[k]; if (k > 0) vkm1 = cval[k - 1]; }
        const int na = (pcv == 1u) ? (kstar + 1) : kstar;
#pragma unroll
        for (int k = 0; k < 8; ++k) if (k < na) { h0 &= rl[k]; h1 &= rh[k]; }
        if (pcv == 1u) { i += kstar + 1; last_val = vk; }
        else { i += kstar; last_val = vkm1; }
        break;
      }
#pragma unroll
      for (int k = 0; k < 8; ++k) if (k < kt) { h0 &= rl[k]; h1 &= rh[k]; }
      i += kt;
      last_val = lastc;
      if (i >= nsel) break;
    }
  }
  const float hit_score = (i == 1) ? mxv : last_val;

  // ---- emission ----
  const int c0n = __popcll(h0), c1n = __popcll(h1);
  int s0 = c0n;
#pragma unroll
  for (int o = 1; o < 64; o <<= 1) {
    int n = __shfl_up(s0, o);
    if (lane >= o) s0 += n;
  }
  const int tot0 = __shfl(s0, 63);
  const int pre0 = s0 - c0n;
  int s1 = c1n;
#pragma unroll
  for (int o = 1; o < 64; o <<= 1) {
    int n = __shfl_up(s1, o);
    if (lane >= o) s1 += n;
  }
  const int tot = tot0 + __shfl(s1, 63);
  const int pre1 = tot0 + s1 - c1n;
  {
    u64 x = h0;
    int r = pre0;
    while (x && r < 5) {
      const int bp = __ffsll((unsigned long long)x) - 1;
      out[OFF_HI + b * 5 + r] = (float)((lane << 6) + bp);
      x &= x - 1;
      ++r;
    }
    x = h1;
    r = pre1;
    while (x && r < 5) {
      const int bp = __ffsll((unsigned long long)x) - 1;
      out[OFF_HI + b * 5 + r] = (float)(((64 + lane) << 6) + bp);
      x &= x - 1;
      ++r;
    }
  }
  int fb = 0x7fffffff;
  if (c0n) fb = (lane << 6) + __ffsll((unsigned long long)h0) - 1;
  else if (c1n) fb = ((64 + lane) << 6) + __ffsll((unsigned long long)h1) - 1;
#pragma unroll
  for (int o = 32; o >= 1; o >>= 1) fb = min(fb, __shfl_xor(fb, o));
  if (lane == 0) {
    const int num_hit = tot < 5 ? tot : 5;
    for (int r = num_hit; r < 5; ++r) out[OFF_HI + b * 5 + r] = -1.0f;
    out[OFF_HS + b] = hit_score;
    const float ci0 = out[OFF_CI + b * 5];
    const float cs0 = out[OFF_CS + b * 5];
    out[OFF_C1 + b] = (num_hit == 1) ? (float)fb : ci0;
    out[OFF_C2 + b] = (cs0 < 0.85f && num_hit == 1) ? (float)fb : ci0;
  }
}

extern "C" void kernel_launch(void* const* d_in, const int* in_sizes, int n_in,
                              void* d_out, int out_size, void* d_ws, size_t ws_size,
                              hipStream_t stream) {
  (void)in_sizes; (void)n_in; (void)out_size; (void)ws_size;
  const float* class_logits = (const float*)d_in[0];
  const float* compo_logits = (const float*)d_in[1];
  const float* co_occ = (const float*)d_in[2];
  const int* mat = (const int*)d_in[3];
  float* out = (float*)d_out;
  u64* packed = (u64*)d_ws;                                   // 1 MB
  float* sc_arr = (float*)((char*)d_ws + (size_t)C_SZ * RW * 8);  // 16.4 MB

  pack_kernel<<<C_SZ, 256, 0, stream>>>(mat, packed);
  class_topk_kernel<<<B_SZ, 256, 0, stream>>>(class_logits, out);
  matvec_kernel<<<B_SZ / S_MV, 256, 0, stream>>>(compo_logits, co_occ, sc_arr);
  tail_kernel<<<B_SZ / 4, 256, 0, stream>>>(sc_arr, packed, out);
}

// Round 5
// 137.946 us; speedup vs baseline: 1.7853x; 1.6161x over previous
//
#include <hip/hip_runtime.h>
#include <cstdint>
#include <cstddef>

typedef unsigned long long u64;

#define B_SZ 4096
#define C_SZ 1000
#define V_SZ 8000
#define RW 128              // padded row stride in u64 (125 used, rest zero)
#define THRESHF 0.8f
#define SCALEF 0.1f

#define OFF_CI 0
#define OFF_CS (B_SZ * 5)
#define OFF_HI (2 * B_SZ * 5)
#define OFF_HS (3 * B_SZ * 5)
#define OFF_C1 (3 * B_SZ * 5 + B_SZ)
#define OFF_C2 (3 * B_SZ * 5 + 2 * B_SZ)

// ---------------- pack matrix rows into bitmasks ----------------
__global__ __launch_bounds__(256) void pack_kernel(const int* __restrict__ mat,
                                                   u64* __restrict__ packed) {
  const int c = blockIdx.x;
  const int tid = threadIdx.x;
  const int lane = tid & 63;
  const int wv = tid >> 6;
  const int* row = mat + (size_t)c * V_SZ;
  for (int base = 0; base < 8192; base += 256) {
    const int k = base + tid;
    int v = 0;
    if (k < V_SZ) v = row[k];
    u64 msk = __ballot(v != 0);
    if (lane == 0) packed[(size_t)c * RW + ((base >> 6) + wv)] = msk;
  }
}

// ---------------- class softmax + top5 (float4 loads) ----------------
__global__ __launch_bounds__(256) void class_topk_kernel(const float* __restrict__ logits,
                                                         float* __restrict__ out) {
  const int b = blockIdx.x;
  const int tid = threadIdx.x;
  const int lane = tid & 63;
  const int wv = tid >> 6;
  const float* row = logits + (size_t)b * V_SZ;
  float v[32];
#pragma unroll
  for (int f = 0; f < 8; ++f) {
    const int base = (f << 10) + (tid << 2);
    if (base < V_SZ) {
      float4 x = *(const float4*)(row + base);
      v[4 * f + 0] = x.x; v[4 * f + 1] = x.y; v[4 * f + 2] = x.z; v[4 * f + 3] = x.w;
    } else {
      v[4 * f + 0] = -INFINITY; v[4 * f + 1] = -INFINITY;
      v[4 * f + 2] = -INFINITY; v[4 * f + 3] = -INFINITY;
    }
  }
  __shared__ float sred[4];
  __shared__ int sredi[4];
  float lm = -INFINITY;
#pragma unroll
  for (int q = 0; q < 32; ++q) lm = fmaxf(lm, v[q]);
#pragma unroll
  for (int o = 32; o >= 1; o >>= 1) lm = fmaxf(lm, __shfl_xor(lm, o));
  if (lane == 0) sred[wv] = lm;
  __syncthreads();
  const float m = fmaxf(fmaxf(sred[0], sred[1]), fmaxf(sred[2], sred[3]));
  float ls = 0.f;
#pragma unroll
  for (int q = 0; q < 32; ++q) ls += expf(v[q] - m);
#pragma unroll
  for (int o = 32; o >= 1; o >>= 1) ls += __shfl_xor(ls, o);
  __syncthreads();
  if (lane == 0) sred[wv] = ls;
  __syncthreads();
  const float ssum = sred[0] + sred[1] + sred[2] + sred[3];
  for (int r = 0; r < 5; ++r) {
    float bv = -INFINITY;
    int bi = 0;
#pragma unroll
    for (int q = 0; q < 32; ++q) {
      const int idx = ((q >> 2) << 10) + (tid << 2) + (q & 3);
      if (v[q] > bv) { bv = v[q]; bi = idx; }
    }
#pragma unroll
    for (int o = 32; o >= 1; o >>= 1) {
      float ov = __shfl_xor(bv, o);
      int oi = __shfl_xor(bi, o);
      if (ov > bv || (ov == bv && oi < bi)) { bv = ov; bi = oi; }
    }
    __syncthreads();
    if (lane == 0) { sred[wv] = bv; sredi[wv] = bi; }
    __syncthreads();
    bv = sred[0]; bi = sredi[0];
#pragma unroll
    for (int w = 1; w < 4; ++w) {
      if (sred[w] > bv || (sred[w] == bv && sredi[w] < bi)) { bv = sred[w]; bi = sredi[w]; }
    }
    if (((bi & 1023) >> 2) == tid) {
      const int sl = ((bi >> 10) << 2) | (bi & 3);
#pragma unroll
      for (int q = 0; q < 32; ++q)
        if (q == sl) v[q] = -INFINITY;
    }
    if (tid == 0) {
      out[OFF_CI + b * 5 + r] = (float)bi;
      out[OFF_CS + b * 5 + r] = expf(bv - m) / ssum;
    }
  }
}

// ---------------- fused decode: matvec (4 samples/block) + tail (wave/sample) ----------------
__global__ __launch_bounds__(256, 4) void decode_kernel(const float* __restrict__ compo_logits,
                                                        const float* __restrict__ co_occ,
                                                        const u64* __restrict__ packed,
                                                        float* __restrict__ out) {
  const int b0 = blockIdx.x * 4;
  const int tid = threadIdx.x;
  const int lane = tid & 63;
  const int w = tid >> 6;
  __shared__ float s_sc[4][C_SZ];    // raw sigmoid
  __shared__ float s_buf[4][C_SZ];   // masked score, later final score
  __shared__ short s_list[1024];
  __shared__ int s_U;

  // ---- phase A: sigmoid ----
  for (int idx = tid; idx < 1000; idx += 256) {
    const int sp = idx / 250;
    const int f = idx - sp * 250;
    float4 x = ((const float4*)(compo_logits + (size_t)(b0 + sp) * C_SZ))[f];
    float v0 = 1.0f / (1.0f + expf(-x.x));
    float v1 = 1.0f / (1.0f + expf(-x.y));
    float v2 = 1.0f / (1.0f + expf(-x.z));
    float v3 = 1.0f / (1.0f + expf(-x.w));
    s_sc[sp][4 * f + 0] = v0; s_buf[sp][4 * f + 0] = v0 > THRESHF ? v0 : 0.0f;
    s_sc[sp][4 * f + 1] = v1; s_buf[sp][4 * f + 1] = v1 > THRESHF ? v1 : 0.0f;
    s_sc[sp][4 * f + 2] = v2; s_buf[sp][4 * f + 2] = v2 > THRESHF ? v2 : 0.0f;
    s_sc[sp][4 * f + 3] = v3; s_buf[sp][4 * f + 3] = v3 > THRESHF ? v3 : 0.0f;
  }
  __syncthreads();
  // ---- phase B: union row list (ascending), wave 0 ----
  if (w == 0) {
    int off = 0;
    for (int base = 0; base < C_SZ; base += 64) {
      const int k = base + lane;
      bool sel = false;
      if (k < C_SZ)
        sel = (s_buf[0][k] != 0.0f) | (s_buf[1][k] != 0.0f) |
              (s_buf[2][k] != 0.0f) | (s_buf[3][k] != 0.0f);
      u64 msk = __ballot(sel);
      int rank = __popcll(msk & ((1ull << lane) - 1ull));
      if (sel) s_list[off + rank] = (short)k;
      off += __popcll(msk);
    }
    if (lane == 0) { s_U = off; s_list[off] = 0; }  // pad for prefetch
  }
  __syncthreads();
  const int U = s_U;

  // ---- phase C: branchless column-owned accumulation ----
  float a00 = 0.f, a01 = 0.f, a02 = 0.f, a03 = 0.f;
  float a10 = 0.f, a11 = 0.f, a12 = 0.f, a13 = 0.f;
  float a20 = 0.f, a21 = 0.f, a22 = 0.f, a23 = 0.f;
  float a30 = 0.f, a31 = 0.f, a32 = 0.f, a33 = 0.f;
  if (tid < 250 && U > 0) {
    const float4* cop = (const float4*)co_occ;
    float4 cv = cop[(size_t)s_list[0] * 250 + tid];
    for (int e = 0; e < U; ++e) {
      const int i = s_list[e];
      const int inext = s_list[e + 1];
      float4 nx = cop[(size_t)inext * 250 + tid];
      const float m0 = s_buf[0][i];
      const float m1 = s_buf[1][i];
      const float m2 = s_buf[2][i];
      const float m3 = s_buf[3][i];
      a00 += m0 * cv.x; a01 += m0 * cv.y; a02 += m0 * cv.z; a03 += m0 * cv.w;
      a10 += m1 * cv.x; a11 += m1 * cv.y; a12 += m1 * cv.z; a13 += m1 * cv.w;
      a20 += m2 * cv.x; a21 += m2 * cv.y; a22 += m2 * cv.z; a23 += m2 * cv.w;
      a30 += m3 * cv.x; a31 += m3 * cv.y; a32 += m3 * cv.z; a33 += m3 * cv.w;
      cv = nx;
    }
  }
  // final scores into regs (reads s_sc only)
  float f00 = 0, f01 = 0, f02 = 0, f03 = 0, f10 = 0, f11 = 0, f12 = 0, f13 = 0;
  float f20 = 0, f21 = 0, f22 = 0, f23 = 0, f30 = 0, f31 = 0, f32 = 0, f33 = 0;
  if (tid < 250) {
    const int cb = tid << 2;
    f00 = s_sc[0][cb + 0] + SCALEF * a00; f01 = s_sc[0][cb + 1] + SCALEF * a01;
    f02 = s_sc[0][cb + 2] + SCALEF * a02; f03 = s_sc[0][cb + 3] + SCALEF * a03;
    f10 = s_sc[1][cb + 0] + SCALEF * a10; f11 = s_sc[1][cb + 1] + SCALEF * a11;
    f12 = s_sc[1][cb + 2] + SCALEF * a12; f13 = s_sc[1][cb + 3] + SCALEF * a13;
    f20 = s_sc[2][cb + 0] + SCALEF * a20; f21 = s_sc[2][cb + 1] + SCALEF * a21;
    f22 = s_sc[2][cb + 2] + SCALEF * a22; f23 = s_sc[2][cb + 3] + SCALEF * a23;
    f30 = s_sc[3][cb + 0] + SCALEF * a30; f31 = s_sc[3][cb + 1] + SCALEF * a31;
    f32 = s_sc[3][cb + 2] + SCALEF * a32; f33 = s_sc[3][cb + 3] + SCALEF * a33;
  }
  __syncthreads();  // all phase-C broadcast reads of s_buf done
  if (tid < 250) {
    const int cb = tid << 2;
    s_buf[0][cb + 0] = f00; s_buf[0][cb + 1] = f01; s_buf[0][cb + 2] = f02; s_buf[0][cb + 3] = f03;
    s_buf[1][cb + 0] = f10; s_buf[1][cb + 1] = f11; s_buf[1][cb + 2] = f12; s_buf[1][cb + 3] = f13;
    s_buf[2][cb + 0] = f20; s_buf[2][cb + 1] = f21; s_buf[2][cb + 2] = f22; s_buf[2][cb + 3] = f23;
    s_buf[3][cb + 0] = f30; s_buf[3][cb + 1] = f31; s_buf[3][cb + 2] = f32; s_buf[3][cb + 3] = f33;
  }
  __syncthreads();

  // ---- phase E: tail, wave w handles sample b0+w (logic identical to R4) ----
  const int b = b0 + w;
  u64 key[16];
  unsigned avail = 0;
  int cnt = 0;
  u64 kb = 0;
#pragma unroll
  for (int q = 0; q < 16; ++q) {
    const int col = lane + (q << 6);
    if (col < C_SZ) {
      const float s = s_buf[w][col];
      const u64 k = ((u64)__float_as_uint(s) << 32) | (u64)(0xFFFFFFFFu - (unsigned)col);
      key[q] = k;
      if (k > kb) kb = k;
      if (s > THRESHF) { avail |= 1u << q; cnt++; }
    } else key[q] = 0;
  }
  u64 mk = kb;
#pragma unroll
  for (int o = 32; o >= 1; o >>= 1) { u64 t = __shfl_xor(mk, o); if (t > mk) mk = t; }
  const float mxv = __uint_as_float((unsigned)(mk >> 32));
  const int mxi = (int)(0xFFFFFFFFu - (unsigned)(mk & 0xFFFFFFFFull));
#pragma unroll
  for (int o = 32; o >= 1; o >>= 1) cnt += __shfl_xor(cnt, o);
  const int nsel = cnt;
  if ((mxi & 63) == lane) avail &= ~(1u << (mxi >> 6));
  const u64* pr = packed + (size_t)mxi * RW;
  u64 h0 = pr[lane], h1 = pr[64 + lane];
  int pc = __popcll(h0) + __popcll(h1);
#pragma unroll
  for (int o = 32; o >= 1; o >>= 1) pc += __shfl_xor(pc, o);
  int i = 1;
  float last_val = mxv;
  if (nsel >= 2 && pc > 1) {
    for (;;) {
      int kt = (nsel - i < 8) ? (nsel - i) : 8;
      float cval[8];
      int cidx[8];
      u64 rl[8], rh[8];
      float lastc = last_val;
      int kv = 0;
#pragma unroll
      for (int k = 0; k < 8; ++k) {
        cval[k] = 0.0f; cidx[k] = -1;
        if (k < kt) {
          u64 lm = 0;
#pragma unroll
          for (int q = 0; q < 16; ++q)
            if (avail & (1u << q)) { if (key[q] > lm) lm = key[q]; }
          u64 ck = lm;
#pragma unroll
          for (int o = 32; o >= 1; o >>= 1) { u64 t = __shfl_xor(ck, o); if (t > ck) ck = t; }
          if (ck != 0) {
            cval[k] = __uint_as_float((unsigned)(ck >> 32));
            cidx[k] = (int)(0xFFFFFFFFu - (unsigned)(ck & 0xFFFFFFFFull));
            if ((cidx[k] & 63) == lane) avail &= ~(1u << (cidx[k] >> 6));
            lastc = cval[k];
            kv = k + 1;
          }
        }
      }
      kt = kv;
      if (kt == 0) break;
#pragma unroll
      for (int k = 0; k < 8; ++k) {
        if (k < kt) {
          const u64* rp = packed + (size_t)cidx[k] * RW;
          rl[k] = rp[lane]; rh[k] = rp[64 + lane];
        } else { rl[k] = ~0ull; rh[k] = ~0ull; }
      }
      u64 c0 = h0, c1 = h1, pk0 = 0, pk1 = 0;
#pragma unroll
      for (int k = 0; k < 8; ++k) {
        c0 &= rl[k]; c1 &= rh[k];
        const u64 p = (u64)(__popcll(c0) + __popcll(c1));
        if (k < 4) pk0 |= p << (k * 16); else pk1 |= p << ((k - 4) * 16);
      }
#pragma unroll
      for (int o = 32; o >= 1; o >>= 1) { pk0 += __shfl_xor(pk0, o); pk1 += __shfl_xor(pk1, o); }
      int kstar = -1;
      unsigned pcv = 0;
#pragma unroll
      for (int k = 0; k < 8; ++k) {
        if (k < kt && kstar < 0) {
          const unsigned f = (unsigned)(((k < 4 ? pk0 : pk1) >> ((k & 3) * 16)) & 0xFFFFull);
          if (f <= 1u) { kstar = k; pcv = f; }
        }
      }
      if (kstar >= 0) {
        float vk = 0.f, vkm1 = last_val;
#pragma unroll
        for (int k = 0; k < 8; ++k)
          if (k == kstar) { vk = cval[k]; if (k > 0) vkm1 = cval[k - 1]; }
        const int na = (pcv == 1u) ? (kstar + 1) : kstar;
#pragma unroll
        for (int k = 0; k < 8; ++k) if (k < na) { h0 &= rl[k]; h1 &= rh[k]; }
        if (pcv == 1u) { i += kstar + 1; last_val = vk; }
        else { i += kstar; last_val = vkm1; }
        break;
      }
#pragma unroll
      for (int k = 0; k < 8; ++k) if (k < kt) { h0 &= rl[k]; h1 &= rh[k]; }
      i += kt;
      last_val = lastc;
      if (i >= nsel) break;
    }
  }
  const float hit_score = (i == 1) ? mxv : last_val;

  const int c0n = __popcll(h0), c1n = __popcll(h1);
  int s0 = c0n;
#pragma unroll
  for (int o = 1; o < 64; o <<= 1) {
    int n = __shfl_up(s0, o);
    if (lane >= o) s0 += n;
  }
  const int tot0 = __shfl(s0, 63);
  const int pre0 = s0 - c0n;
  int s1 = c1n;
#pragma unroll
  for (int o = 1; o < 64; o <<= 1) {
    int n = __shfl_up(s1, o);
    if (lane >= o) s1 += n;
  }
  const int tot = tot0 + __shfl(s1, 63);
  const int pre1 = tot0 + s1 - c1n;
  {
    u64 x = h0;
    int r = pre0;
    while (x && r < 5) {
      const int bp = __ffsll((unsigned long long)x) - 1;
      out[OFF_HI + b * 5 + r] = (float)((lane << 6) + bp);
      x &= x - 1;
      ++r;
    }
    x = h1;
    r = pre1;
    while (x && r < 5) {
      const int bp = __ffsll((unsigned long long)x) - 1;
      out[OFF_HI + b * 5 + r] = (float)(((64 + lane) << 6) + bp);
      x &= x - 1;
      ++r;
    }
  }
  int fb = 0x7fffffff;
  if (c0n) fb = (lane << 6) + __ffsll((unsigned long long)h0) - 1;
  else if (c1n) fb = ((64 + lane) << 6) + __ffsll((unsigned long long)h1) - 1;
#pragma unroll
  for (int o = 32; o >= 1; o >>= 1) fb = min(fb, __shfl_xor(fb, o));
  if (lane == 0) {
    const int num_hit = tot < 5 ? tot : 5;
    for (int r = num_hit; r < 5; ++r) out[OFF_HI + b * 5 + r] = -1.0f;
    out[OFF_HS + b] = hit_score;
    const float ci0 = out[OFF_CI + b * 5];
    const float cs0 = out[OFF_CS + b * 5];
    out[OFF_C1 + b] = (num_hit == 1) ? (float)fb : ci0;
    out[OFF_C2 + b] = (cs0 < 0.85f && num_hit == 1) ? (float)fb : ci0;
  }
}

extern "C" void kernel_launch(void* const* d_in, const int* in_sizes, int n_in,
                              void* d_out, int out_size, void* d_ws, size_t ws_size,
                              hipStream_t stream) {
  (void)in_sizes; (void)n_in; (void)out_size; (void)ws_size;
  const float* class_logits = (const float*)d_in[0];
  const float* compo_logits = (const float*)d_in[1];
  const float* co_occ = (const float*)d_in[2];
  const int* mat = (const int*)d_in[3];
  float* out = (float*)d_out;
  u64* packed = (u64*)d_ws;  // 1 MB

  pack_kernel<<<C_SZ, 256, 0, stream>>>(mat, packed);
  class_topk_kernel<<<B_SZ, 256, 0, stream>>>(class_logits, out);
  decode_kernel<<<B_SZ / 4, 256, 0, stream>>>(compo_logits, co_occ, packed, out);
}